// Round 5
// baseline (265.113 us; speedup 1.0000x reference)
//
#include <hip/hip_runtime.h>
#include <math.h>

#define SDIM 3
#define BDIM 32
#define NPRI 2000
#define LDIM 4
#define DDIM 78
#define NOFF 72
#define NSB (SDIM * BDIM)     // 96
#define PPB 512               // priors per block (256 thr x 2)
#define NCHUNK 4              // 4*512 = 2048 >= 2000

// ws layout:
//   chunkTop float2[2][96][4][4][4] : 98,304 B  (val, bitcast idx), lex top-4
//   clsSum   f[2][2000]             : 16,000 B  (atomic, memset 0)
//   corrws   f[2][2000]             : 16,000 B  (atomic, memset 0)
//   regacc   f[2][8]                :     64 B  (atomic, memset 0)
//   rowsws   i[2][4]                :     32 B  (written unconditionally)

__device__ __forceinline__ void lexmin_bfly(float& v, int& i) {
#pragma unroll
    for (int off = 32; off > 0; off >>= 1) {
        float v2 = __shfl_xor(v, off);
        int   i2 = __shfl_xor(i, off);
        if (v2 < v || (v2 == v && i2 < i)) { v = v2; i = i2; }
    }
}

// ---------------------------------------------------------------------------
// cost: grid (4, 96, 2), block 256. Thread owns priors (2t, 2t+1) of chunk.
// Direct global->register float4 streaming; no big LDS; per-block lex top-4.
__global__ __launch_bounds__(256) void cost_kernel(
    const float* __restrict__ predsA, const float* __restrict__ predsB,
    const float* __restrict__ gt, float2* __restrict__ chunkTop,
    float* __restrict__ clsSum)
{
    const int chunk = blockIdx.x;
    const int sb = blockIdx.y;
    const int branch = blockIdx.z;
    const float* preds = branch ? predsB : predsA;
    const int bimg = sb % BDIM;
    const int tid = threadIdx.x;
    const int wv = tid >> 6, lane = tid & 63;

    __shared__ float tgdiv[NOFF][4];       // t/799 per (j, l)
    __shared__ float ggeo[LDIM][4];        // raw gt geo
    __shared__ float wtv[4][LDIM][4];      // per-wave top4 vals
    __shared__ int   wti[4][LDIM][4];

    // stage targets (exact same division as reference)
    if (tid < 256) { int j = tid >> 2, l = tid & 3;
        tgdiv[j][l] = gt[((size_t)bimg * LDIM + l) * DDIM + 6 + j] / 799.0f; }
    if (tid < 32)  { int k = 256 + tid; int j = k >> 2, l = k & 3;
        tgdiv[j][l] = gt[((size_t)bimg * LDIM + l) * DDIM + 6 + j] / 799.0f; }
    if (tid >= 32 && tid < 48) { int idx = tid - 32; int l = idx >> 2, d = idx & 3;
        ggeo[l][d] = gt[((size_t)bimg * LDIM + l) * DDIM + 2 + d]; }
    __syncthreads();

    const int pr0 = chunk * PPB + 2 * tid;        // even
    const bool act = (pr0 < NPRI);

    float a[2], bb[2], g[2][4];
    float offs[2][4] = {{0.f,0.f,0.f,0.f},{0.f,0.f,0.f,0.f}};

    if (act) {
        const float4* b4 = (const float4*)(preds + ((size_t)sb * NPRI + pr0) * DDIM);
#pragma unroll
        for (int q = 0; q < 39; ++q) {
            float4 v = b4[q];
            float vv[4] = {v.x, v.y, v.z, v.w};
#pragma unroll
            for (int k = 0; k < 4; ++k) {
                const int f = 4 * q + k;
                const int p = (f >= DDIM) ? 1 : 0;
                const int pos = f - DDIM * p;
                float x = vv[k];
                if (pos == 0) a[p] = x;
                else if (pos == 1) bb[p] = x;
                else if (pos < 6) g[p][pos - 2] = x;
                else {
                    const int j = pos - 6;
#pragma unroll
                    for (int l = 0; l < LDIM; ++l) offs[p][l] += fabsf(x - tgdiv[j][l]);
                }
            }
        }
    }

    // per-prior cost + negative focal term
    float c[2][LDIM];
#pragma unroll
    for (int p = 0; p < 2; ++p) {
        if (act) {
            float m = fmaxf(a[p], bb[p]);
            float ea = expf(a[p] - m), eb = expf(bb[p] - m);
            float score = eb / (ea + eb);
#pragma unroll
            for (int l = 0; l < LDIM; ++l) {
                float geo = fabsf(g[p][0] - ggeo[l][0]) + fabsf(g[p][1] - ggeo[l][1])
                          + fabsf(g[p][2] - ggeo[l][2]) + fabsf(g[p][3] - ggeo[l][3]);
                c[p][l] = geo + offs[p][l] / 72.0f - score;
            }
            float lse = m + logf(ea + eb);
            float logpt = a[p] - lse;
            float pt = expf(logpt);
            float om = 1.0f - pt;
            atomicAdd(&clsSum[branch * NPRI + pr0 + p], -(0.1f * om * om * logpt));
        } else {
#pragma unroll
            for (int l = 0; l < LDIM; ++l) c[p][l] = INFINITY;
        }
    }

    // wave-level lex top-4 per l (2 candidates per lane)
#pragma unroll
    for (int l = 0; l < LDIM; ++l) {
        float c0 = c[0][l], c1 = c[1][l];
        int   i0 = pr0, i1 = pr0 + 1;
        bool  m0 = !act, m1 = !act;
#pragma unroll
        for (int r = 0; r < 4; ++r) {
            float lv; int li;
            // lane-local lex-min of unmasked (i0 < i1 always)
            if (!m0 && (m1 || c0 <= c1)) { lv = c0; li = i0; }
            else if (!m1)                { lv = c1; li = i1; }
            else                         { lv = INFINITY; li = 0x7fffffff; }
            lexmin_bfly(lv, li);
            if (lane == 0) { wtv[wv][l][r] = lv; wti[wv][l][r] = li; }
            if (li == i0) m0 = true;
            if (li == i1) m1 = true;
        }
    }
    __syncthreads();

    // cross-wave merge: wave l merges list l (16 candidates in lanes 0..15)
    {
        const int l = wv;
        float v = INFINITY; int i = 0x7fffffff;
        if (lane < 16) { v = wtv[lane >> 2][l][lane & 3]; i = wti[lane >> 2][l][lane & 3]; }
        float outv[4]; int outi[4];
#pragma unroll
        for (int r = 0; r < 4; ++r) {
            float lv = v; int li = i;
            lexmin_bfly(lv, li);
            outv[r] = lv; outi[r] = li;
            if (li == i) v = INFINITY;   // mask owner (indices unique)
        }
        if (lane == 0) {
            float2* dst = chunkTop + ((((size_t)(branch * NSB + sb)) * LDIM + l) * NCHUNK + chunk) * 4;
#pragma unroll
            for (int r = 0; r < 4; ++r) dst[r] = make_float2(outv[r], __int_as_float(outi[r]));
        }
    }
}

// ---------------------------------------------------------------------------
// merge + greedy + regiou + matched focal corr. grid (96,2), 64 threads.
__global__ __launch_bounds__(64) void merge_kernel(
    const float* __restrict__ predsA, const float* __restrict__ predsB,
    const float* __restrict__ gt, const float2* __restrict__ chunkTop,
    int* __restrict__ rowsws, float* __restrict__ regacc,
    float* __restrict__ corrws)
{
    const int sb = blockIdx.x, branch = blockIdx.y;
    const float* preds = branch ? predsB : predsA;
    const int lane = threadIdx.x;
    const int bimg = sb % BDIM;

    __shared__ float tops_v[LDIM][4];
    __shared__ int   tops_i[LDIM][4];
    __shared__ int   rows_lds[LDIM];

    // global top-4 per l from the 4 chunks' top-4 lists
    for (int l = 0; l < LDIM; ++l) {
        float v = INFINITY; int i = 0x7fffffff;
        if (lane < 16) {
            float2 e = chunkTop[((((size_t)(branch * NSB + sb)) * LDIM + l) * NCHUNK + (lane >> 2)) * 4 + (lane & 3)];
            v = e.x; i = __float_as_int(e.y);
        }
#pragma unroll
        for (int r = 0; r < 4; ++r) {
            float lv = v; int li = i;
            lexmin_bfly(lv, li);
            if (lane == 0) { tops_v[l][r] = lv; tops_i[l][r] = li; }
            if (li == i) v = INFINITY;
        }
    }
    __syncthreads();

    // greedy over 16 candidates (exact jnp semantics)
    if (lane == 0) {
        int used[LDIM];
#pragma unroll
        for (int l = 0; l < LDIM; ++l) {
            int pick = tops_i[l][3];
#pragma unroll
            for (int r = 3; r >= 0; --r) {
                int cand = tops_i[l][r];
                bool ok = true;
                for (int u = 0; u < l; ++u) ok = ok && (used[u] != cand);
                if (ok) pick = cand;     // reverse scan: last ok = first in lex order
            }
            used[l] = pick;
            rows_lds[l] = pick;
        }
    }
    __syncthreads();
    if (sb == NSB - 1 && lane < LDIM) rowsws[branch * LDIM + lane] = rows_lds[lane];

    // regiou + matched focal corr, one row at a time (wave-coalesced reads)
    for (int l = 0; l < LDIM; ++l) {
        const int row = rows_lds[l];
        const float* pm = preds + ((size_t)sb * NPRI + row) * DDIM;
        const float* tg = gt + ((size_t)bimg * LDIM + l) * DDIM;

        float osum = 0.f, usum = 0.f, rterm = 0.f;
        {
            float rp = pm[6 + lane] * 799.0f;
            float rt = tg[6 + lane];
            bool inv = (rt < 0.0f) || (rt >= 800.0f);
            float ov = fminf(rp, rt) - fmaxf(rp, rt) + 30.0f;
            float un = fmaxf(rp, rt) - fminf(rp, rt) + 30.0f;
            if (!inv) { osum += ov; usum += un; }
        }
        if (lane < 8) {
            float rp = pm[70 + lane] * 799.0f;
            float rt = tg[70 + lane];
            bool inv = (rt < 0.0f) || (rt >= 800.0f);
            float ov = fminf(rp, rt) - fmaxf(rp, rt) + 30.0f;
            float un = fmaxf(rp, rt) - fminf(rp, rt) + 30.0f;
            if (!inv) { osum += ov; usum += un; }
        }
        if (lane < 4) {
            const float scv[4] = {71.0f, 799.0f, 180.0f, 71.0f};
            float s = scv[lane];
            float d = pm[2 + lane] * s - tg[2 + lane] * s;
            float ad = fabsf(d);
            rterm = (ad < 1.0f) ? 0.5f * d * d : ad - 0.5f;
        }
#pragma unroll
        for (int off = 32; off > 0; off >>= 1) {
            osum += __shfl_down(osum, off);
            usum += __shfl_down(usum, off);
            rterm += __shfl_down(rterm, off);
        }
        if (lane == 0) {
            float iou = osum / (usum + 1e-9f);
            atomicAdd(&regacc[branch * 8 + l], (rterm / 4.0f) / 4.0f);
            atomicAdd(&regacc[branch * 8 + 4 + l], (1.0f - iou) / 4.0f);

            float a = pm[0], b1 = pm[1];
            float m = fmaxf(a, b1);
            float ea = expf(a - m), eb = expf(b1 - m);
            float lse = m + logf(ea + eb);
            float lp0 = a - lse, lp1 = b1 - lse;
            float pt0 = expf(lp0), pt1 = expf(lp1);
            float om0 = 1.0f - pt0, om1 = 1.0f - pt1;
            float neg = -(0.1f * om0 * om0 * lp0);
            float pos = -(0.9f * om1 * om1 * lp1);
            atomicAdd(&corrws[branch * NPRI + row], pos - neg);
        }
    }
}

// ---------------------------------------------------------------------------
// final: inst vectors, exact median (bitonic 2048), weighted sum -> scalar.
__global__ __launch_bounds__(1024) void final_kernel(
    const float* __restrict__ clsSum, const float* __restrict__ corrws,
    const float* __restrict__ regacc, const int* __restrict__ rowsws,
    const float* __restrict__ diff, float* __restrict__ out)
{
    __shared__ float instA[NPRI];
    __shared__ float instB[NPRI];
    __shared__ float sbuf[2048];
    __shared__ float red[1024];
    const int tid = threadIdx.x;

    for (int n = tid; n < NPRI; n += 1024) {
        float ia = (clsSum[n] + corrws[n]) * (2.0f / 96.0f);
        float ib = (clsSum[NPRI + n] + corrws[NPRI + n]) * (2.0f / 96.0f);
#pragma unroll
        for (int l = 0; l < 4; ++l) {
            if (rowsws[l] == n)
                ia += (regacc[l] / 96.0f) * 0.5f + (regacc[4 + l] / 96.0f) * 2.0f;
            if (rowsws[4 + l] == n)
                ib += (regacc[8 + l] / 96.0f) * 0.5f + (regacc[12 + l] / 96.0f) * 2.0f;
        }
        instA[n] = ia; instB[n] = ib;
        sbuf[n] = ia - ib;
    }
    if (tid < 2048 - NPRI) sbuf[NPRI + tid] = INFINITY;
    __syncthreads();

    for (int k = 2; k <= 2048; k <<= 1) {
        for (int j = k >> 1; j > 0; j >>= 1) {
            for (int i = tid; i < 2048; i += 1024) {
                int ixj = i ^ j;
                if (ixj > i) {
                    bool up = ((i & k) == 0);
                    float x = sbuf[i], y = sbuf[ixj];
                    if ((x > y) == up) { sbuf[i] = y; sbuf[ixj] = x; }
                }
            }
            __syncthreads();
        }
    }
    float delta = 0.5f * (sbuf[999] + sbuf[1000]);

    float acc = 0.0f;
    for (int n = tid; n < NPRI; n += 1024) {
        float dm = (diff[n] + diff[NPRI + n] + diff[2 * NPRI + n]) / 3.0f;
        acc += (1.0f - dm) * (instA[n] - 0.5f * delta)
             + dm * (instB[n] + 0.5f * delta);
    }
    red[tid] = acc;
    __syncthreads();
    for (int s = 512; s > 0; s >>= 1) {
        if (tid < s) red[tid] += red[tid + s];
        __syncthreads();
    }
    if (tid == 0) out[0] = red[0];
}

// ---------------------------------------------------------------------------
extern "C" void kernel_launch(void* const* d_in, const int* in_sizes, int n_in,
                              void* d_out, int out_size, void* d_ws, size_t ws_size,
                              hipStream_t stream)
{
    const float* predsA = (const float*)d_in[0];
    const float* predsB = (const float*)d_in[1];
    const float* gt     = (const float*)d_in[2];
    const float* diff   = (const float*)d_in[3];
    float* out = (float*)d_out;

    float2* chunkTop = (float2*)d_ws;                       // 12,288 float2
    float*  clsSum   = (float*)((char*)d_ws + 98304);       // 4,000 f
    float*  corrws   = clsSum + 2 * NPRI;                   // 4,000 f
    float*  regacc   = corrws + 2 * NPRI;                   // 16 f
    int*    rowsws   = (int*)(regacc + 16);                 // 8 i

    // zero the atomic accumulators (32,064 B contiguous)
    hipMemsetAsync(clsSum, 0, (2 * NPRI + 2 * NPRI + 16) * sizeof(float), stream);

    dim3 g1(NCHUNK, NSB, 2);
    cost_kernel<<<g1, 256, 0, stream>>>(predsA, predsB, gt, chunkTop, clsSum);

    dim3 g2(NSB, 2);
    merge_kernel<<<g2, 64, 0, stream>>>(predsA, predsB, gt, chunkTop,
                                        rowsws, regacc, corrws);

    final_kernel<<<1, 1024, 0, stream>>>(clsSum, corrws, regacc, rowsws, diff, out);
}

// Round 6
// 247.012 us; speedup vs baseline: 1.0733x; 1.0733x over previous
//
#include <hip/hip_runtime.h>
#include <math.h>

#define SDIM 3
#define BDIM 32
#define NPRI 2000
#define LDIM 4
#define DDIM 78
#define NOFF 72
#define NSB (SDIM * BDIM)     // 96
#define CHUNK 64
#define NCHUNK 32             // 32*64 = 2048 >= 2000

// ws layout:
//   chunkTop float2[2][96][4][32][4] : 786,432 B (val, bitcast idx) lex top-4/chunk
//   clsSum   f[2][2000]              :  16,000 B (atomic, memset 0)
//   corrws   f[2][2000]              :  16,000 B (atomic, memset 0)
//   regacc   f[2][8]                 :      64 B (atomic, memset 0)
//   rowsws   i[2][4]                 :      32 B

__device__ __forceinline__ void lexmin_bfly(float& v, int& i) {
#pragma unroll
    for (int off = 32; off > 0; off >>= 1) {
        float v2 = __shfl_xor(v, off);
        int   i2 = __shfl_xor(i, off);
        if (v2 < v || (v2 == v && i2 < i)) { v = v2; i = i2; }
    }
}

// ---------------------------------------------------------------------------
// cost: grid (32, 96, 2), block 256. Coalesced float4 staging of 64 priors
// (19,968 B LDS -> 7 blocks/CU). Lane-group of 4 per prior, j-quarters
// combined via shfl_xor. Per-chunk lex top-4 per target l -> chunkTop.
__global__ __launch_bounds__(256) void cost_kernel(
    const float* __restrict__ predsA, const float* __restrict__ predsB,
    const float* __restrict__ gt, float2* __restrict__ chunkTop,
    float* __restrict__ clsSum)
{
    const int chunk = blockIdx.x;
    const int sb = blockIdx.y;
    const int branch = blockIdx.z;
    const float* preds = branch ? predsB : predsA;
    const int bimg = sb % BDIM;
    const int tid = threadIdx.x;
    const int wv = tid >> 6, lane = tid & 63;
    const int base_n = chunk * CHUNK;
    const int ntile = min(CHUNK, NPRI - base_n);   // 64, except 16 on chunk 31

    __shared__ float tile[CHUNK * DDIM];   // 19,968 B
    __shared__ float tgdiv[NOFF * 4];      //  1,152 B : [j][l] = t/799
    __shared__ float ggeo[LDIM][4];        //     64 B
    __shared__ float wtv[4][LDIM][4];      // per-wave top4
    __shared__ int   wti[4][LDIM][4];

    // stage targets
    if (tid < 256) { int j = tid >> 2, l = tid & 3;
        tgdiv[j * 4 + l] = gt[((size_t)bimg * LDIM + l) * DDIM + 6 + j] / 799.0f; }
    if (tid < 32)  { int k = 256 + tid; int j = k >> 2, l = k & 3;
        tgdiv[j * 4 + l] = gt[((size_t)bimg * LDIM + l) * DDIM + 6 + j] / 799.0f; }
    if (tid >= 32 && tid < 48) { int idx = tid - 32; int l = idx >> 2, d = idx & 3;
        ggeo[l][d] = gt[((size_t)bimg * LDIM + l) * DDIM + 2 + d]; }

    // coalesced staging of the prior tile
    {
        const float4* src = (const float4*)(preds + ((size_t)sb * NPRI + base_n) * DDIM);
        float4* dst = (float4*)tile;
        const int nf4 = ntile * DDIM / 4;          // 1248 or 312
        for (int k = tid; k < nf4; k += 256) dst[k] = src[k];
    }
    __syncthreads();

    const int i = (wv << 4) + (lane >> 2);         // prior within chunk
    const int h = lane & 3;                        // j-quarter
    const int n = base_n + i;
    const bool act = (i < ntile);

    float offs[4] = {0.f, 0.f, 0.f, 0.f};
    if (act) {
        const float* p = &tile[i * DDIM];
        const int j0 = 18 * h;
#pragma unroll
        for (int k = 0; k < 18; k += 2) {
            float pv0 = p[6 + j0 + k];
            float pv1 = p[7 + j0 + k];
            const float* t0 = &tgdiv[(j0 + k) * 4];
            const float* t1 = &tgdiv[(j0 + k + 1) * 4];
#pragma unroll
            for (int l = 0; l < 4; ++l) {
                offs[l] += fabsf(pv0 - t0[l]);
                offs[l] += fabsf(pv1 - t1[l]);
            }
        }
    }
    // combine quarters within the 4-lane group (all lanes participate)
#pragma unroll
    for (int l = 0; l < 4; ++l) {
        offs[l] += __shfl_xor(offs[l], 1);
        offs[l] += __shfl_xor(offs[l], 2);
    }

    float c[4] = {INFINITY, INFINITY, INFINITY, INFINITY};
    const bool own = act && (h == 0);
    if (own) {
        const float* p = &tile[i * DDIM];
        float a = p[0], b1 = p[1];
        float m = fmaxf(a, b1);
        float ea = expf(a - m), eb = expf(b1 - m);
        float score = eb / (ea + eb);
        float g0 = p[2], g1 = p[3], g2 = p[4], g3 = p[5];
#pragma unroll
        for (int l = 0; l < 4; ++l) {
            float geo = fabsf(g0 - ggeo[l][0]) + fabsf(g1 - ggeo[l][1])
                      + fabsf(g2 - ggeo[l][2]) + fabsf(g3 - ggeo[l][3]);
            c[l] = geo + offs[l] / 72.0f - score;
        }
        float lse = m + logf(ea + eb);
        float logpt = a - lse;
        float pt = expf(logpt);
        float om = 1.0f - pt;
        atomicAdd(&clsSum[branch * NPRI + n], -(0.1f * om * om * logpt));
    }

    // wave-level lex top-4 per l (candidates on h==0 lanes)
    const int ci0 = own ? n : 0x7fffffff;
#pragma unroll
    for (int l = 0; l < 4; ++l) {
        float cv = c[l]; int ci = ci0;
#pragma unroll
        for (int r = 0; r < 4; ++r) {
            float lv = cv; int li = ci;
            lexmin_bfly(lv, li);
            if (lane == 0) { wtv[wv][l][r] = lv; wti[wv][l][r] = li; }
            if (li == ci) cv = INFINITY;
        }
    }
    __syncthreads();

    // cross-wave merge: wave l merges list l (16 candidates)
    {
        const int l = wv;
        float v = INFINITY; int id = 0x7fffffff;
        if (lane < 16) { v = wtv[lane >> 2][l][lane & 3]; id = wti[lane >> 2][l][lane & 3]; }
#pragma unroll
        for (int r = 0; r < 4; ++r) {
            float lv = v; int li = id;
            lexmin_bfly(lv, li);
            if (lane == 0)
                chunkTop[((((size_t)(branch * NSB + sb)) * LDIM + l) * NCHUNK + chunk) * 4 + r]
                    = make_float2(lv, __int_as_float(li));
            if (li == id) v = INFINITY;
        }
    }
}

// ---------------------------------------------------------------------------
// merge + greedy + regiou + matched focal corr. grid (96,2), 64 threads.
__global__ __launch_bounds__(64) void merge_kernel(
    const float* __restrict__ predsA, const float* __restrict__ predsB,
    const float* __restrict__ gt, const float2* __restrict__ chunkTop,
    int* __restrict__ rowsws, float* __restrict__ regacc,
    float* __restrict__ corrws)
{
    const int sb = blockIdx.x, branch = blockIdx.y;
    const float* preds = branch ? predsB : predsA;
    const int lane = threadIdx.x;
    const int bimg = sb % BDIM;

    __shared__ float tops_v[LDIM][4];
    __shared__ int   tops_i[LDIM][4];
    __shared__ int   rows_lds[LDIM];

    // global top-4 per l from 128 chunk candidates (2 per lane)
    for (int l = 0; l < LDIM; ++l) {
        const float2* base = chunkTop + (((size_t)(branch * NSB + sb)) * LDIM + l) * (NCHUNK * 4);
        float2 e0 = base[lane], e1 = base[64 + lane];
        float v0 = e0.x, v1 = e1.x;
        int   i0 = __float_as_int(e0.y), i1 = __float_as_int(e1.y);
        bool  m0 = false, m1 = false;
#pragma unroll
        for (int r = 0; r < 4; ++r) {
            float lv; int li;
            if (!m0 && (m1 || v0 < v1 || (v0 == v1 && i0 < i1))) { lv = v0; li = i0; }
            else if (!m1) { lv = v1; li = i1; }
            else { lv = INFINITY; li = 0x7fffffff; }
            lexmin_bfly(lv, li);
            if (lane == 0) { tops_v[l][r] = lv; tops_i[l][r] = li; }
            if (li == i0) m0 = true;
            if (li == i1) m1 = true;
        }
    }
    __syncthreads();

    // greedy over 16 candidates (exact jnp argmin-without-replacement)
    if (lane == 0) {
        int used[LDIM];
#pragma unroll
        for (int l = 0; l < LDIM; ++l) {
            int pick = tops_i[l][3];
#pragma unroll
            for (int r = 3; r >= 0; --r) {
                int cand = tops_i[l][r];
                bool ok = true;
                for (int u = 0; u < l; ++u) ok = ok && (used[u] != cand);
                if (ok) pick = cand;     // reverse scan: last ok = lex-first
            }
            used[l] = pick;
            rows_lds[l] = pick;
        }
    }
    __syncthreads();
    if (sb == NSB - 1 && lane < LDIM) rowsws[branch * LDIM + lane] = rows_lds[lane];

    // regiou + matched focal corr (wave-coalesced row reads)
    for (int l = 0; l < LDIM; ++l) {
        const int row = rows_lds[l];
        const float* pm = preds + ((size_t)sb * NPRI + row) * DDIM;
        const float* tg = gt + ((size_t)bimg * LDIM + l) * DDIM;

        float osum = 0.f, usum = 0.f, rterm = 0.f;
        {
            float rp = pm[6 + lane] * 799.0f;
            float rt = tg[6 + lane];
            bool inv = (rt < 0.0f) || (rt >= 800.0f);
            float ov = fminf(rp, rt) - fmaxf(rp, rt) + 30.0f;
            float un = fmaxf(rp, rt) - fminf(rp, rt) + 30.0f;
            if (!inv) { osum += ov; usum += un; }
        }
        if (lane < 8) {
            float rp = pm[70 + lane] * 799.0f;
            float rt = tg[70 + lane];
            bool inv = (rt < 0.0f) || (rt >= 800.0f);
            float ov = fminf(rp, rt) - fmaxf(rp, rt) + 30.0f;
            float un = fmaxf(rp, rt) - fminf(rp, rt) + 30.0f;
            if (!inv) { osum += ov; usum += un; }
        }
        if (lane < 4) {
            const float scv[4] = {71.0f, 799.0f, 180.0f, 71.0f};
            float s = scv[lane];
            float d = pm[2 + lane] * s - tg[2 + lane] * s;
            float ad = fabsf(d);
            rterm = (ad < 1.0f) ? 0.5f * d * d : ad - 0.5f;
        }
#pragma unroll
        for (int off = 32; off > 0; off >>= 1) {
            osum += __shfl_down(osum, off);
            usum += __shfl_down(usum, off);
            rterm += __shfl_down(rterm, off);
        }
        if (lane == 0) {
            float iou = osum / (usum + 1e-9f);
            atomicAdd(&regacc[branch * 8 + l], (rterm / 4.0f) / 4.0f);
            atomicAdd(&regacc[branch * 8 + 4 + l], (1.0f - iou) / 4.0f);

            float a = pm[0], b1 = pm[1];
            float m = fmaxf(a, b1);
            float ea = expf(a - m), eb = expf(b1 - m);
            float lse = m + logf(ea + eb);
            float lp0 = a - lse, lp1 = b1 - lse;
            float pt0 = expf(lp0), pt1 = expf(lp1);
            float om0 = 1.0f - pt0, om1 = 1.0f - pt1;
            float neg = -(0.1f * om0 * om0 * lp0);
            float pos = -(0.9f * om1 * om1 * lp1);
            atomicAdd(&corrws[branch * NPRI + row], pos - neg);
        }
    }
}

// ---------------------------------------------------------------------------
__device__ __forceinline__ float key_unflip(unsigned int u) {
    unsigned int s = (u & 0x80000000u) ? (u ^ 0x80000000u) : ~u;
    return __uint_as_float(s);
}

// final: inst values on the fly, exact median via radix-256 select (ranks
// 999 & 1000), delta folded algebraically. 1 block, 256 threads.
__global__ __launch_bounds__(256) void final_kernel(
    const float* __restrict__ clsSum, const float* __restrict__ corrws,
    const float* __restrict__ regacc, const int* __restrict__ rowsws,
    const float* __restrict__ diff, float* __restrict__ out)
{
    __shared__ unsigned int keyu[NPRI];     // 8,000 B
    __shared__ unsigned int hist[256];
    __shared__ unsigned int wsum[4];
    __shared__ int selb, selr;
    __shared__ float fred[8];
    const int tid = threadIdx.x;
    const int wv = tid >> 6, lane = tid & 63;

    float rA[8], rB[8]; int rwA[4], rwB[4];
#pragma unroll
    for (int k = 0; k < 8; ++k) { rA[k] = regacc[k]; rB[k] = regacc[8 + k]; }
#pragma unroll
    for (int k = 0; k < 4; ++k) { rwA[k] = rowsws[k]; rwB[k] = rowsws[4 + k]; }

    float acc0 = 0.f, acc1 = 0.f;
    for (int n = tid; n < NPRI; n += 256) {
        float ia = (clsSum[n] + corrws[n]) * (2.0f / 96.0f);
        float ib = (clsSum[NPRI + n] + corrws[NPRI + n]) * (2.0f / 96.0f);
#pragma unroll
        for (int l = 0; l < 4; ++l) {
            if (rwA[l] == n) ia += (rA[l] / 96.0f) * 0.5f + (rA[4 + l] / 96.0f) * 2.0f;
            if (rwB[l] == n) ib += (rB[l] / 96.0f) * 0.5f + (rB[4 + l] / 96.0f) * 2.0f;
        }
        float dm = (diff[n] + diff[NPRI + n] + diff[2 * NPRI + n]) / 3.0f;
        acc0 += (1.0f - dm) * ia + dm * ib;
        acc1 += 2.0f * dm - 1.0f;
        float d = ia - ib;
        unsigned int s = __float_as_uint(d);
        keyu[n] = s ^ ((s >> 31) ? 0xFFFFFFFFu : 0x80000000u);
    }
    __syncthreads();

    // exact radix-256 select of ranks 999 and 1000 (ascending)
    unsigned int kv[2];
    for (int t = 0; t < 2; ++t) {
        int rank = 999 + t;
        unsigned int prefix = 0, pmask = 0;
        for (int shift = 24; shift >= 0; shift -= 8) {
            hist[tid] = 0;
            __syncthreads();
            for (int n = tid; n < NPRI; n += 256) {
                unsigned int k = keyu[n];
                if ((k & pmask) == prefix) atomicAdd(&hist[(k >> shift) & 255], 1u);
            }
            __syncthreads();
            unsigned int cnt = hist[tid];
            unsigned int x = cnt;
#pragma unroll
            for (int s = 1; s < 64; s <<= 1) {
                unsigned int y = __shfl_up(x, s);
                if (lane >= s) x += y;
            }
            if (lane == 63) wsum[wv] = x;
            __syncthreads();
            unsigned int off = 0;
            for (int w = 0; w < wv; ++w) off += wsum[w];
            unsigned int incl = x + off, excl = incl - cnt;
            if ((int)excl <= rank && rank < (int)incl) { selb = tid; selr = rank - (int)excl; }
            __syncthreads();
            prefix |= ((unsigned int)selb << shift);
            rank = selr;
            pmask |= (0xFFu << shift);
            __syncthreads();
        }
        kv[t] = prefix;
    }
    float delta = 0.5f * (key_unflip(kv[0]) + key_unflip(kv[1]));

    // block reduce acc0/acc1
#pragma unroll
    for (int off = 32; off > 0; off >>= 1) {
        acc0 += __shfl_down(acc0, off);
        acc1 += __shfl_down(acc1, off);
    }
    if (lane == 0) { fred[wv] = acc0; fred[4 + wv] = acc1; }
    __syncthreads();
    if (tid == 0) {
        float a0 = fred[0] + fred[1] + fred[2] + fred[3];
        float a1 = fred[4] + fred[5] + fred[6] + fred[7];
        out[0] = a0 + 0.5f * delta * a1;
    }
}

// ---------------------------------------------------------------------------
extern "C" void kernel_launch(void* const* d_in, const int* in_sizes, int n_in,
                              void* d_out, int out_size, void* d_ws, size_t ws_size,
                              hipStream_t stream)
{
    const float* predsA = (const float*)d_in[0];
    const float* predsB = (const float*)d_in[1];
    const float* gt     = (const float*)d_in[2];
    const float* diff   = (const float*)d_in[3];
    float* out = (float*)d_out;

    float2* chunkTop = (float2*)d_ws;                       // 98,304 float2
    float*  clsSum   = (float*)((char*)d_ws + 786432);      // 4,000 f
    float*  corrws   = clsSum + 2 * NPRI;                   // 4,000 f
    float*  regacc   = corrws + 2 * NPRI;                   // 16 f
    int*    rowsws   = (int*)(regacc + 16);                 // 8 i

    hipMemsetAsync(clsSum, 0, (2 * NPRI + 2 * NPRI + 16) * sizeof(float), stream);

    dim3 g1(NCHUNK, NSB, 2);
    cost_kernel<<<g1, 256, 0, stream>>>(predsA, predsB, gt, chunkTop, clsSum);

    dim3 g2(NSB, 2);
    merge_kernel<<<g2, 64, 0, stream>>>(predsA, predsB, gt, chunkTop,
                                        rowsws, regacc, corrws);

    final_kernel<<<1, 256, 0, stream>>>(clsSum, corrws, regacc, rowsws, diff, out);
}

// Round 7
// 237.042 us; speedup vs baseline: 1.1184x; 1.0421x over previous
//
#include <hip/hip_runtime.h>
#include <math.h>

#define NPRI 2000
#define LDIM 4
#define DDIM 78
#define NOFF 72
#define NSB 96
#define CHUNK 128
#define NCH 16            // 16*128 = 2048 >= 2000
#define NBLK (NSB * 2)    // 192 blocks, one per (sb, branch)

// ws layout (16B-aligned sections):
//   ticket  int[4]        (16 B)   \
//   clsSum  f[2][2000]             |  zeroed by one hipMemsetAsync (32,112 B)
//   corrws  f[2][2000]             |
//   regacc  f[2][8]                |
//   rowsws  i[2][4]                /
//   tgdiv   f[32][72][4]  (36,864 B)  gt offsets / 799, [b][j][l]

__device__ __forceinline__ void lexmin_bfly(float& v, int& i) {
#pragma unroll
    for (int off = 32; off > 0; off >>= 1) {
        float v2 = __shfl_xor(v, off);
        int   i2 = __shfl_xor(i, off);
        if (v2 < v || (v2 == v && i2 < i)) { v = v2; i = i2; }
    }
}

// ---------------------------------------------------------------------------
__global__ __launch_bounds__(256) void prep_kernel(
    const float* __restrict__ gt, float* __restrict__ tgdiv)
{
    int t = blockIdx.x * 256 + threadIdx.x;      // 32*72*4 = 9216
    if (t < 32 * NOFF * 4) {
        int b = t / (NOFF * 4), r = t % (NOFF * 4), j = r >> 2, l = r & 3;
        tgdiv[t] = gt[((size_t)b * LDIM + l) * DDIM + 6 + j] / 799.0f;
    }
}

// ---------------------------------------------------------------------------
__global__ __launch_bounds__(1024, 4) void main_kernel(
    const float* __restrict__ predsA, const float* __restrict__ predsB,
    const float* __restrict__ gt, const float* __restrict__ tgdiv,
    int* __restrict__ ticket, float* __restrict__ clsSum,
    float* __restrict__ corrws, float* __restrict__ regacc,
    int* __restrict__ rowsws, const float* __restrict__ diff,
    float* __restrict__ out)
{
    const int sb = blockIdx.x, branch = blockIdx.y;
    const float* preds = branch ? predsB : predsA;
    const int bimg = sb & 31;
    const int tid = threadIdx.x;
    const int wv = tid >> 6, lane = tid & 63;

    __shared__ float tile[CHUNK * DDIM];      // 39,936 B
    __shared__ float wtv[16][LDIM][4];
    __shared__ int   wti[16][LDIM][4];
    __shared__ int   lastflag;
    __shared__ unsigned keyu[NPRI];           // 8,000 B (phase 3)
    __shared__ unsigned hist[256];
    __shared__ unsigned wsum[4];
    __shared__ int selb, selr;
    __shared__ float fred[32];

    const float* pb  = preds + (size_t)sb * NPRI * DDIM;
    const float* tgb = tgdiv + (size_t)bimg * NOFF * 4;      // L1-hot vec loads
    const float* gtb = gt + (size_t)bimg * LDIM * DDIM;      // uniform -> s_load

    const int iloc = (wv << 3) + (lane >> 3);  // prior within chunk, 0..127
    const int h = lane & 7;                    // j-ninth
    const int j0 = h * 9;

    // per-lane running top-4 per l (meaningful on h==0 lanes)
    float tv[4][4]; int ti_[4][4];
#pragma unroll
    for (int l = 0; l < 4; ++l)
#pragma unroll
        for (int r = 0; r < 4; ++r) { tv[l][r] = INFINITY; ti_[l][r] = 0x7fffffff; }

    // ---------------- phase 1: cost + top4 + neg focal ----------------
    const float4* src4 = (const float4*)pb;
    float4 r0, r1, r2;
    {
        const int nf4 = CHUNK * DDIM / 4;      // 2496
        if (tid < nf4) r0 = src4[tid];
        if (tid + 1024 < nf4) r1 = src4[tid + 1024];
        if (tid + 2048 < nf4) r2 = src4[tid + 2048];
    }
    for (int c = 0; c < NCH; ++c) {
        const int ntile = min(CHUNK, NPRI - c * CHUNK);   // 128, last 80
        const int nf4 = ntile * DDIM / 4;
        __syncthreads();                       // prior compute done
        {
            float4* dst = (float4*)tile;
            if (tid < nf4) dst[tid] = r0;
            if (tid + 1024 < nf4) dst[tid + 1024] = r1;
            if (tid + 2048 < nf4) dst[tid + 2048] = r2;
        }
        if (c + 1 < NCH) {                     // prefetch next chunk
            const int ntn = min(CHUNK, NPRI - (c + 1) * CHUNK);
            const int nfn = ntn * DDIM / 4;
            const int b4 = (c + 1) * (CHUNK * DDIM / 4);
            if (tid < nfn) r0 = src4[b4 + tid];
            if (tid + 1024 < nfn) r1 = src4[b4 + tid + 1024];
            if (tid + 2048 < nfn) r2 = src4[b4 + tid + 2048];
        }
        __syncthreads();                       // tile ready
        if (iloc < ntile) {
            const float* p = &tile[iloc * DDIM];
            float o0 = 0.f, o1 = 0.f, o2 = 0.f, o3 = 0.f;
            const float* tj = tgb + j0 * 4;
#pragma unroll
            for (int j = 0; j < 9; ++j) {
                float pv = p[6 + j0 + j];
                o0 += fabsf(pv - tj[j * 4 + 0]);
                o1 += fabsf(pv - tj[j * 4 + 1]);
                o2 += fabsf(pv - tj[j * 4 + 2]);
                o3 += fabsf(pv - tj[j * 4 + 3]);
            }
            // combine the 8 j-ninths (group = lanes sharing lane>>3)
            o0 += __shfl_xor(o0, 1); o1 += __shfl_xor(o1, 1);
            o2 += __shfl_xor(o2, 1); o3 += __shfl_xor(o3, 1);
            o0 += __shfl_xor(o0, 2); o1 += __shfl_xor(o1, 2);
            o2 += __shfl_xor(o2, 2); o3 += __shfl_xor(o3, 2);
            o0 += __shfl_xor(o0, 4); o1 += __shfl_xor(o1, 4);
            o2 += __shfl_xor(o2, 4); o3 += __shfl_xor(o3, 4);

            if (h == 0) {
                const int n = c * CHUNK + iloc;
                float a = p[0], b1 = p[1];
                float m = fmaxf(a, b1);
                float ea = expf(a - m), eb = expf(b1 - m);
                float score = eb / (ea + eb);
                float lse = m + logf(ea + eb);
                float logpt = a - lse;
                float pt = expf(logpt);
                float om = 1.0f - pt;
                atomicAdd(&clsSum[branch * NPRI + n], -(0.1f * om * om * logpt));

                float pg0 = p[2], pg1 = p[3], pg2 = p[4], pg3 = p[5];
                float offs[4] = {o0, o1, o2, o3};
#pragma unroll
                for (int l = 0; l < 4; ++l) {
                    float geo = fabsf(pg0 - gtb[l * DDIM + 2]) + fabsf(pg1 - gtb[l * DDIM + 3])
                              + fabsf(pg2 - gtb[l * DDIM + 4]) + fabsf(pg3 - gtb[l * DDIM + 5]);
                    float cst = geo + offs[l] / 72.0f - score;
                    float* V = tv[l]; int* I = ti_[l];
                    bool lt3 = cst < V[3] || (cst == V[3] && n < I[3]);
                    if (lt3) {
                        bool lt0 = cst < V[0] || (cst == V[0] && n < I[0]);
                        bool lt1 = cst < V[1] || (cst == V[1] && n < I[1]);
                        bool lt2 = cst < V[2] || (cst == V[2] && n < I[2]);
                        if (lt0) { V[3]=V[2];I[3]=I[2]; V[2]=V[1];I[2]=I[1]; V[1]=V[0];I[1]=I[0]; V[0]=cst;I[0]=n; }
                        else if (lt1) { V[3]=V[2];I[3]=I[2]; V[2]=V[1];I[2]=I[1]; V[1]=cst;I[1]=n; }
                        else if (lt2) { V[3]=V[2];I[3]=I[2]; V[2]=cst;I[2]=n; }
                        else { V[3]=cst; I[3]=n; }
                    }
                }
            }
        }
    }

    // wave-level top-4 per l (4 rounds of pop+bfly; once per block)
    {
        int pc[4] = {0, 0, 0, 0};
#pragma unroll
        for (int l = 0; l < 4; ++l) {
#pragma unroll
            for (int r = 0; r < 4; ++r) {
                float hv = (pc[l]==0)?tv[l][0]:(pc[l]==1)?tv[l][1]:(pc[l]==2)?tv[l][2]:(pc[l]==3)?tv[l][3]:INFINITY;
                int   hi = (pc[l]==0)?ti_[l][0]:(pc[l]==1)?ti_[l][1]:(pc[l]==2)?ti_[l][2]:(pc[l]==3)?ti_[l][3]:0x7fffffff;
                float lv = hv; int li = hi;
                lexmin_bfly(lv, li);
                if (lane == 0) { wtv[wv][l][r] = lv; wti[wv][l][r] = li; }
                if (li == hi && li != 0x7fffffff) pc[l]++;
            }
        }
    }
    __syncthreads();

    // ---------------- phase 2: cross-wave merge + greedy + regiou ----------
    if (wv == 0) {
        float topsv[4][4]; int topsi[4][4];
#pragma unroll
        for (int l = 0; l < 4; ++l) {
            float v = wtv[lane >> 2][l][lane & 3];
            int   i = wti[lane >> 2][l][lane & 3];
#pragma unroll
            for (int r = 0; r < 4; ++r) {
                float lv = v; int li = i;
                lexmin_bfly(lv, li);
                topsv[l][r] = lv; topsi[l][r] = li;   // same in all lanes
                if (li == i) v = INFINITY;
            }
        }
        // greedy without replacement (exact jnp.argmin order, <=3 masked)
        int rowsv[4];
        rowsv[0] = topsi[0][0];
        {
            int pick = topsi[1][3];
#pragma unroll
            for (int r = 3; r >= 0; --r) { int c2 = topsi[1][r]; if (c2 != rowsv[0]) pick = c2; }
            rowsv[1] = pick;
        }
        {
            int pick = topsi[2][3];
#pragma unroll
            for (int r = 3; r >= 0; --r) { int c2 = topsi[2][r]; if (c2 != rowsv[0] && c2 != rowsv[1]) pick = c2; }
            rowsv[2] = pick;
        }
        {
            int pick = topsi[3][3];
#pragma unroll
            for (int r = 3; r >= 0; --r) { int c2 = topsi[3][r]; if (c2 != rowsv[0] && c2 != rowsv[1] && c2 != rowsv[2]) pick = c2; }
            rowsv[3] = pick;
        }
        if (sb == NSB - 1 && lane == 0) {
#pragma unroll
            for (int l = 0; l < 4; ++l) atomicExch(&rowsws[branch * LDIM + l], rowsv[l]);
        }
        // regiou + matched focal correction
#pragma unroll
        for (int l = 0; l < 4; ++l) {
            const int row = rowsv[l];
            const float* pm = pb + (size_t)row * DDIM;
            const float* tg = gtb + l * DDIM;
            float osum = 0.f, usum = 0.f, rterm = 0.f;
            {
                float rp = pm[6 + lane] * 799.0f;
                float rt = tg[6 + lane];
                bool inv = (rt < 0.0f) || (rt >= 800.0f);
                float ov = fminf(rp, rt) - fmaxf(rp, rt) + 30.0f;
                float un = fmaxf(rp, rt) - fminf(rp, rt) + 30.0f;
                if (!inv) { osum += ov; usum += un; }
            }
            if (lane < 8) {
                float rp = pm[70 + lane] * 799.0f;
                float rt = tg[70 + lane];
                bool inv = (rt < 0.0f) || (rt >= 800.0f);
                float ov = fminf(rp, rt) - fmaxf(rp, rt) + 30.0f;
                float un = fmaxf(rp, rt) - fminf(rp, rt) + 30.0f;
                if (!inv) { osum += ov; usum += un; }
            }
            if (lane < 4) {
                const float scv[4] = {71.0f, 799.0f, 180.0f, 71.0f};
                float s = scv[lane];
                float d = pm[2 + lane] * s - tg[2 + lane] * s;
                float ad = fabsf(d);
                rterm = (ad < 1.0f) ? 0.5f * d * d : ad - 0.5f;
            }
#pragma unroll
            for (int off = 32; off > 0; off >>= 1) {
                osum += __shfl_down(osum, off);
                usum += __shfl_down(usum, off);
                rterm += __shfl_down(rterm, off);
            }
            if (lane == 0) {
                float iou = osum / (usum + 1e-9f);
                atomicAdd(&regacc[branch * 8 + l], (rterm / 4.0f) / 4.0f);
                atomicAdd(&regacc[branch * 8 + 4 + l], (1.0f - iou) / 4.0f);
                float a = pm[0], b1 = pm[1];
                float m = fmaxf(a, b1);
                float ea = expf(a - m), eb = expf(b1 - m);
                float lse = m + logf(ea + eb);
                float lp0 = a - lse, lp1 = b1 - lse;
                float pt0 = expf(lp0), pt1 = expf(lp1);
                float om0 = 1.0f - pt0, om1 = 1.0f - pt1;
                float neg = -(0.1f * om0 * om0 * lp0);
                float pos = -(0.9f * om1 * om1 * lp1);
                atomicAdd(&corrws[branch * NPRI + row], pos - neg);
            }
        }
    }
    __syncthreads();   // drains every wave's vmem (incl. atomics) pre-ticket

    // ---------------- ticket: last block does the reduction ----------------
    if (tid == 0) {
        __threadfence();
        int old = atomicAdd(ticket, 1);
        lastflag = (old == NBLK - 1) ? 1 : 0;
    }
    __syncthreads();
    if (!lastflag) return;
    __threadfence();   // acquire: see all blocks' atomics/stores

    // ---------------- phase 3: inst, exact median, total -------------------
    float rA[8], rB[8]; int rwA[4], rwB[4];
#pragma unroll
    for (int k = 0; k < 8; ++k) { rA[k] = regacc[k]; rB[k] = regacc[8 + k]; }
#pragma unroll
    for (int k = 0; k < 4; ++k) { rwA[k] = rowsws[k]; rwB[k] = rowsws[4 + k]; }

    float acc0 = 0.f, acc1 = 0.f;
    for (int n = tid; n < NPRI; n += 1024) {
        float ia = (clsSum[n] + corrws[n]) * (2.0f / 96.0f);
        float ib = (clsSum[NPRI + n] + corrws[NPRI + n]) * (2.0f / 96.0f);
#pragma unroll
        for (int l = 0; l < 4; ++l) {
            if (rwA[l] == n) ia += (rA[l] / 96.0f) * 0.5f + (rA[4 + l] / 96.0f) * 2.0f;
            if (rwB[l] == n) ib += (rB[l] / 96.0f) * 0.5f + (rB[4 + l] / 96.0f) * 2.0f;
        }
        float dm = (diff[n] + diff[NPRI + n] + diff[2 * NPRI + n]) / 3.0f;
        acc0 += (1.0f - dm) * ia + dm * ib;
        acc1 += 2.0f * dm - 1.0f;
        float d = ia - ib;
        unsigned s = __float_as_uint(d);
        keyu[n] = s ^ ((s >> 31) ? 0xFFFFFFFFu : 0x80000000u);
    }
    __syncthreads();

    unsigned kv[2];
    for (int t = 0; t < 2; ++t) {
        int rank = 999 + t;
        unsigned prefix = 0, pmask = 0;
        for (int shift = 24; shift >= 0; shift -= 8) {
            if (tid < 256) hist[tid] = 0;
            __syncthreads();
            for (int n = tid; n < NPRI; n += 1024) {
                unsigned k = keyu[n];
                if ((k & pmask) == prefix) atomicAdd(&hist[(k >> shift) & 255], 1u);
            }
            __syncthreads();
            unsigned cnt = 0, x = 0;
            if (tid < 256) {
                cnt = hist[tid];
                x = cnt;
#pragma unroll
                for (int s = 1; s < 64; s <<= 1) {
                    unsigned y = __shfl_up(x, s);
                    if (lane >= s) x += y;
                }
                if (lane == 63) wsum[wv] = x;
            }
            __syncthreads();
            if (tid < 256) {
                unsigned off = 0;
                for (int w = 0; w < wv; ++w) off += wsum[w];
                unsigned incl = x + off, excl = incl - cnt;
                if ((int)excl <= rank && rank < (int)incl) { selb = tid; selr = rank - (int)excl; }
            }
            __syncthreads();
            prefix |= ((unsigned)selb << shift);
            rank = selr;
            pmask |= (0xFFu << shift);
            __syncthreads();
        }
        kv[t] = prefix;
    }
    auto unflip = [](unsigned u) {
        unsigned s = (u & 0x80000000u) ? (u ^ 0x80000000u) : ~u;
        return __uint_as_float(s);
    };
    float delta = 0.5f * (unflip(kv[0]) + unflip(kv[1]));

#pragma unroll
    for (int off = 32; off > 0; off >>= 1) {
        acc0 += __shfl_down(acc0, off);
        acc1 += __shfl_down(acc1, off);
    }
    if (lane == 0) { fred[wv] = acc0; fred[16 + wv] = acc1; }
    __syncthreads();
    if (tid == 0) {
        float a0 = 0.f, a1 = 0.f;
#pragma unroll
        for (int w = 0; w < 16; ++w) { a0 += fred[w]; a1 += fred[16 + w]; }
        out[0] = a0 + 0.5f * delta * a1;
    }
}

// ---------------------------------------------------------------------------
extern "C" void kernel_launch(void* const* d_in, const int* in_sizes, int n_in,
                              void* d_out, int out_size, void* d_ws, size_t ws_size,
                              hipStream_t stream)
{
    const float* predsA = (const float*)d_in[0];
    const float* predsB = (const float*)d_in[1];
    const float* gt     = (const float*)d_in[2];
    const float* diff   = (const float*)d_in[3];
    float* out = (float*)d_out;

    int*   ticket = (int*)d_ws;
    float* clsSum = (float*)d_ws + 4;
    float* corrws = clsSum + 2 * NPRI;
    float* regacc = corrws + 2 * NPRI;
    int*   rowsws = (int*)(regacc + 16);
    float* tgdiv  = (float*)(rowsws + 8);

    // zero ticket + atomic accumulators in one shot (32,112 B)
    hipMemsetAsync(d_ws, 0, (4 + 4 * NPRI + 16 + 8) * sizeof(float), stream);

    prep_kernel<<<36, 256, 0, stream>>>(gt, tgdiv);

    dim3 g(NSB, 2);
    main_kernel<<<g, 1024, 0, stream>>>(predsA, predsB, gt, tgdiv, ticket,
                                        clsSum, corrws, regacc, rowsws, diff, out);
}